// Round 1
// baseline (652.846 us; speedup 1.0000x reference)
//
#include <hip/hip_runtime.h>
#include <math.h>

#define B_   32
#define T_   1024
#define IN_  512
#define HID_ 512
#define HYP_ 256
#define M_   (B_ * T_)   // 32768

// Tiled fp32 GEMM:  C[M,N] = act( A[M,K] @ B[N,K]^T + bias[N] )  (* mul[M,N] if MUL)
// Weights are stored [N,K] row-major (as in the reference einsums), so
// C[m,n] = sum_k A[m,k] * Bw[n,k].
// ACT: 0 = none, 1 = relu, 2 = sigmoid
template <int ACT, bool MUL>
__global__ __launch_bounds__(256) void gemm_bt(const float* __restrict__ A,
                                               const float* __restrict__ Bw,
                                               const float* __restrict__ bias,
                                               const float* __restrict__ mul,
                                               float* __restrict__ C,
                                               int M, int N, int K)
{
    __shared__ float As[8][128];   // k-major
    __shared__ float Bs[8][128];

    const int tid  = threadIdx.x;
    const int row0 = blockIdx.x * 128;
    const int col0 = blockIdx.y * 128;
    const int tx   = tid & 15;        // N direction (16 threads)
    const int ty   = tid >> 4;        // M direction (16 threads)
    const int lrow = tid >> 1;        // 0..127 — tile row loaded by this thread
    const int lk   = (tid & 1) * 4;   // k sub-offset 0 or 4

    float acc[8][8];
#pragma unroll
    for (int i = 0; i < 8; ++i)
#pragma unroll
        for (int j = 0; j < 8; ++j) acc[i][j] = 0.f;

    const float* Aload = A  + (size_t)(row0 + lrow) * K + lk;
    const float* Bload = Bw + (size_t)(col0 + lrow) * K + lk;

    for (int k0 = 0; k0 < K; k0 += 8) {
        float4 av = *(const float4*)(Aload + k0);
        float4 bv = *(const float4*)(Bload + k0);
        As[lk + 0][lrow] = av.x; As[lk + 1][lrow] = av.y;
        As[lk + 2][lrow] = av.z; As[lk + 3][lrow] = av.w;
        Bs[lk + 0][lrow] = bv.x; Bs[lk + 1][lrow] = bv.y;
        Bs[lk + 2][lrow] = bv.z; Bs[lk + 3][lrow] = bv.w;
        __syncthreads();

#pragma unroll
        for (int k = 0; k < 8; ++k) {
            float a[8], bb[8];
            *(float4*)&a[0]  = *(const float4*)&As[k][ty * 8];
            *(float4*)&a[4]  = *(const float4*)&As[k][ty * 8 + 4];
            *(float4*)&bb[0] = *(const float4*)&Bs[k][tx * 8];
            *(float4*)&bb[4] = *(const float4*)&Bs[k][tx * 8 + 4];
#pragma unroll
            for (int i = 0; i < 8; ++i)
#pragma unroll
                for (int j = 0; j < 8; ++j)
                    acc[i][j] = fmaf(a[i], bb[j], acc[i][j]);
        }
        __syncthreads();
    }

    // Epilogue: bias + activation (+ elementwise multiply), vectorized stores.
    float bvals[8];
#pragma unroll
    for (int j = 0; j < 8; ++j) bvals[j] = bias[col0 + tx * 8 + j];

#pragma unroll
    for (int i = 0; i < 8; ++i) {
        const int row = row0 + ty * 8 + i;
        float out[8];
#pragma unroll
        for (int j = 0; j < 8; ++j) {
            float v = acc[i][j] + bvals[j];
            if (ACT == 1) v = fmaxf(v, 0.f);
            if (ACT == 2) v = 1.f / (1.f + expf(-v));
            out[j] = v;
        }
        float* cp = C + (size_t)row * N + col0 + tx * 8;
        if (MUL) {
            const float* mp = mul + (size_t)row * N + col0 + tx * 8;
            float4 m0 = *(const float4*)mp;
            float4 m1 = *(const float4*)(mp + 4);
            out[0] *= m0.x; out[1] *= m0.y; out[2] *= m0.z; out[3] *= m0.w;
            out[4] *= m1.x; out[5] *= m1.y; out[6] *= m1.z; out[7] *= m1.w;
        }
        *(float4*)cp       = make_float4(out[0], out[1], out[2], out[3]);
        *(float4*)(cp + 4) = make_float4(out[4], out[5], out[6], out[7]);
    }
}

// Sequential scan: h_t = relu(roll(h_{t-1}, 1) + b_t), in-place over the b
// buffer (each [t] row is read once then overwritten by the same thread).
// One wave per batch; each lane owns 8 contiguous h columns in registers.
// The roll-by-1 needs only the previous lane's last element (wave shuffle).
// b rows are prefetched 8 deep in registers; pipeline indices are
// compile-time constants (explicit unroll-by-8).
__global__ __launch_bounds__(64) void srnn_scan(const float* __restrict__ hidden,
                                                float* __restrict__ bio,
                                                float* __restrict__ hlast)
{
    const int b    = blockIdx.x;
    const int lane = threadIdx.x;
    float* bp = bio + (size_t)b * T_ * HID_ + lane * 8;

    float h[8];
    {
        float4 a = *(const float4*)(hidden + b * HID_ + lane * 8);
        float4 c = *(const float4*)(hidden + b * HID_ + lane * 8 + 4);
        h[0] = a.x; h[1] = a.y; h[2] = a.z; h[3] = a.w;
        h[4] = c.x; h[5] = c.y; h[6] = c.z; h[7] = c.w;
    }

    float4 pf0[8], pf1[8];
#pragma unroll
    for (int u = 0; u < 8; ++u) {
        pf0[u] = *(const float4*)(bp + (size_t)u * HID_);
        pf1[u] = *(const float4*)(bp + (size_t)u * HID_ + 4);
    }

    const int src = (lane + 63) & 63;   // lane - 1 (mod 64)

    for (int tb = 0; tb < T_; tb += 8) {
#pragma unroll
        for (int u = 0; u < 8; ++u) {
            const int t = tb + u;
            float4 v0 = pf0[u], v1 = pf1[u];
            if (t + 8 < T_) {   // uniform branch
                pf0[u] = *(const float4*)(bp + (size_t)(t + 8) * HID_);
                pf1[u] = *(const float4*)(bp + (size_t)(t + 8) * HID_ + 4);
            }
            const float carry = __shfl(h[7], src, 64);  // old h[lane*8 - 1] (wraps)
            const float n0 = fmaxf(carry + v0.x, 0.f);
            const float n1 = fmaxf(h[0] + v0.y, 0.f);
            const float n2 = fmaxf(h[1] + v0.z, 0.f);
            const float n3 = fmaxf(h[2] + v0.w, 0.f);
            const float n4 = fmaxf(h[3] + v1.x, 0.f);
            const float n5 = fmaxf(h[4] + v1.y, 0.f);
            const float n6 = fmaxf(h[5] + v1.z, 0.f);
            const float n7 = fmaxf(h[6] + v1.w, 0.f);
            h[0] = n0; h[1] = n1; h[2] = n2; h[3] = n3;
            h[4] = n4; h[5] = n5; h[6] = n6; h[7] = n7;
            *(float4*)(bp + (size_t)t * HID_)     = make_float4(h[0], h[1], h[2], h[3]);
            *(float4*)(bp + (size_t)t * HID_ + 4) = make_float4(h[4], h[5], h[6], h[7]);
        }
    }

    *(float4*)(hlast + b * HID_ + lane * 8)     = make_float4(h[0], h[1], h[2], h[3]);
    *(float4*)(hlast + b * HID_ + lane * 8 + 4) = make_float4(h[4], h[5], h[6], h[7]);
}

extern "C" void kernel_launch(void* const* d_in, const int* in_sizes, int n_in,
                              void* d_out, int out_size, void* d_ws, size_t ws_size,
                              hipStream_t stream)
{
    const float* x      = (const float*)d_in[0];  // [B,T,IN]
    const float* hidden = (const float*)d_in[1];  // [B,HID]
    const float* Ws     = (const float*)d_in[2];  // [HYP,IN]
    const float* bs     = (const float*)d_in[3];  // [HYP]
    const float* Wm     = (const float*)d_in[4];  // [HYP,HYP]
    const float* bm     = (const float*)d_in[5];  // [HYP]
    const float* We     = (const float*)d_in[6];  // [HID,HYP]
    const float* be     = (const float*)d_in[7];  // [HID]
    const float* W2     = (const float*)d_in[8];  // [HID,IN]
    const float* b2     = (const float*)d_in[9];  // [HID]

    float* outputs = (float*)d_out;                      // [B,T,HID]
    float* hlast   = outputs + (size_t)M_ * HID_;        // [B,HID]

    float* h1 = (float*)d_ws;                            // [M, HYP]  32 MB
    float* h2 = h1 + (size_t)M_ * HYP_;                  // [M, HYP]  32 MB

    const dim3 blk(256);

    // h1 = relu(x @ Ws^T + bs)
    gemm_bt<1, false><<<dim3(M_ / 128, HYP_ / 128), blk, 0, stream>>>(
        x, Ws, bs, nullptr, h1, M_, HYP_, IN_);
    // h2 = relu(h1 @ Wm^T + bm)
    gemm_bt<1, false><<<dim3(M_ / 128, HYP_ / 128), blk, 0, stream>>>(
        h1, Wm, bm, nullptr, h2, M_, HYP_, HYP_);
    // outputs = h2 @ We^T + be            (fc_end, staged in d_out)
    gemm_bt<0, false><<<dim3(M_ / 128, HID_ / 128), blk, 0, stream>>>(
        h2, We, be, nullptr, outputs, M_, HID_, HYP_);
    // outputs = sigmoid(x @ W2^T + b2) * outputs     (b = fc_end * sig, in place)
    gemm_bt<2, true><<<dim3(M_ / 128, HID_ / 128), blk, 0, stream>>>(
        x, W2, b2, outputs, outputs, M_, HID_, IN_);
    // scan: outputs[t] = h_t (in place), hlast = h_{T-1}
    srnn_scan<<<dim3(B_), dim3(64), 0, stream>>>(hidden, outputs, hlast);
}

// Round 3
// 229.629 us; speedup vs baseline: 2.8430x; 2.8430x over previous
//
#include <hip/hip_runtime.h>
#include <math.h>

#define B_   32
#define T_   1024
#define IN_  512
#define HID_ 512
#define HYP_ 256
#define M_   (B_ * T_)   // 32768

typedef _Float16 half8_t __attribute__((ext_vector_type(8)));
typedef float    f32x4   __attribute__((ext_vector_type(4)));

typedef __attribute__((address_space(1))) const void* gptr_as1;
typedef __attribute__((address_space(3))) void*       lptr_as3;

__device__ __forceinline__ void gload_lds16(const void* g, void* l) {
    // async global->LDS, 16 bytes per lane; LDS dest = wave-uniform base + lane*16
    __builtin_amdgcn_global_load_lds((gptr_as1)g, (lptr_as3)l, 16, 0, 0);
}

// Split fp32 weights into fp16 (hi, lo) pair: w == hi + lo to ~2^-22 rel.
__global__ void split_w(const float* __restrict__ w, _Float16* __restrict__ hi,
                        _Float16* __restrict__ lo, int n)
{
    int i = blockIdx.x * 256 + threadIdx.x;
    if (i < n) {
        float v = w[i];
        _Float16 h = (_Float16)v;
        hi[i] = h;
        lo[i] = (_Float16)(v - (float)h);
    }
}

// ---------------------------------------------------------------------------
// MFMA fp16 GEMM with 2-term weight split (extended K' = 2K: [W_hi | W_lo],
// A repeated). C = relu(A @ W^T + bias), C stored fp16.
// 128x128 tile, BK=32, 4 waves (2x2), each wave 64x64 via 4x4 frags of
// mfma_f32_16x16x32_f16. A path: AF16 ? global_load_lds : fp32 load+convert.
// ---------------------------------------------------------------------------

// stage a [128 rows x 32 halfs] tile from f16 src (row stride K halfs) into lds
__device__ __forceinline__ void stage_f16_tile(const _Float16* src_r0k, int K,
                                               _Float16* lds, int tid)
{
    const int wave = tid >> 6;
    const char* sb = (const char*)src_r0k;
#pragma unroll
    for (int q = 0; q < 2; ++q) {
        int c = q * 256 + tid;
        int row = c >> 2;
        int inrow = (c & 3) * 16;
        const void* g = sb + (size_t)row * (K * 2) + inrow;
        void* l = (char*)lds + (q * 256 + wave * 64) * 16;
        gload_lds16(g, l);
    }
}

// stage a [128 rows x 32 halfs] tile converted from f32 src (row stride K floats)
__device__ __forceinline__ void stage_f32cvt_tile(const float* src_r0k, int K,
                                                  _Float16* lds, int tid)
{
    const int row = tid >> 1;
    const int kh = (tid & 1) * 16;
    const float* s = src_r0k + (size_t)row * K + kh;
    f32x4 v0 = *(const f32x4*)(s);
    f32x4 v1 = *(const f32x4*)(s + 4);
    f32x4 v2 = *(const f32x4*)(s + 8);
    f32x4 v3 = *(const f32x4*)(s + 12);
    half8_t h0, h1;
    h0[0] = (_Float16)v0[0]; h0[1] = (_Float16)v0[1];
    h0[2] = (_Float16)v0[2]; h0[3] = (_Float16)v0[3];
    h0[4] = (_Float16)v1[0]; h0[5] = (_Float16)v1[1];
    h0[6] = (_Float16)v1[2]; h0[7] = (_Float16)v1[3];
    h1[0] = (_Float16)v2[0]; h1[1] = (_Float16)v2[1];
    h1[2] = (_Float16)v2[2]; h1[3] = (_Float16)v2[3];
    h1[4] = (_Float16)v3[0]; h1[5] = (_Float16)v3[1];
    h1[6] = (_Float16)v3[2]; h1[7] = (_Float16)v3[3];
    *(half8_t*)(lds + row * 32 + kh)     = h0;
    *(half8_t*)(lds + row * 32 + kh + 8) = h1;
}

template <bool AF16>
__global__ __launch_bounds__(256) void gemm_relu_f16out(
    const float* __restrict__ Af32, const _Float16* __restrict__ Af16,
    const _Float16* __restrict__ Whi, const _Float16* __restrict__ Wlo,
    const float* __restrict__ bias, _Float16* __restrict__ Cout,
    int N, int K)
{
    __shared__ __align__(16) _Float16 As[128 * 32];
    __shared__ __align__(16) _Float16 Bs[128 * 32];

    const int tid = threadIdx.x;
    const int m0 = blockIdx.x * 128;
    const int n0 = blockIdx.y * 128;
    const int wave = tid >> 6, lane = tid & 63;
    const int wr = wave >> 1, wc = wave & 1;
    const int lq = lane >> 4, lr = lane & 15;

    f32x4 zero = {0.f, 0.f, 0.f, 0.f};
    f32x4 acc[4][4];
#pragma unroll
    for (int i = 0; i < 4; ++i)
#pragma unroll
        for (int j = 0; j < 4; ++j) acc[i][j] = zero;

    const int extK = 2 * K;
    for (int kk = 0; kk < extK; kk += 32) {
        const int ksrc = kk & (K - 1);
        const _Float16* Wseg = (kk < K) ? Whi : Wlo;
        stage_f16_tile(Wseg + (size_t)n0 * K + ksrc, K, Bs, tid);
        if (AF16) stage_f16_tile(Af16 + (size_t)m0 * K + ksrc, K, As, tid);
        else      stage_f32cvt_tile(Af32 + (size_t)m0 * K + ksrc, K, As, tid);
        __syncthreads();

        half8_t af[4], wf[4];
#pragma unroll
        for (int i = 0; i < 4; ++i)
            af[i] = *(const half8_t*)(As + (wr * 64 + i * 16 + lr) * 32 + lq * 8);
#pragma unroll
        for (int j = 0; j < 4; ++j)
            wf[j] = *(const half8_t*)(Bs + (wc * 64 + j * 16 + lr) * 32 + lq * 8);
#pragma unroll
        for (int i = 0; i < 4; ++i)
#pragma unroll
            for (int j = 0; j < 4; ++j)
                acc[i][j] = __builtin_amdgcn_mfma_f32_16x16x32_f16(af[i], wf[j], acc[i][j], 0, 0, 0);
        __syncthreads();
    }

#pragma unroll
    for (int j = 0; j < 4; ++j) {
        const int col = n0 + wc * 64 + j * 16 + lr;
        const float bv = bias[col];
#pragma unroll
        for (int i = 0; i < 4; ++i) {
            const int rbase = m0 + wr * 64 + i * 16 + lq * 4;
#pragma unroll
            for (int rg = 0; rg < 4; ++rg) {
                float v = acc[i][j][rg] + bv;
                v = fmaxf(v, 0.f);
                Cout[(size_t)(rbase + rg) * N + col] = (_Float16)v;
            }
        }
    }
}

// ---------------------------------------------------------------------------
// Fused G3+G4: Out = (h2 @ We^T + be) * sigmoid(x @ W2^T + b2), fp32 out.
// Two sequential K-loops into two accumulator sets, shared LDS.
// ---------------------------------------------------------------------------
__global__ __launch_bounds__(256) void gemm_g34(
    const _Float16* __restrict__ h2h,                              // [M,256] f16
    const _Float16* __restrict__ Wehi, const _Float16* __restrict__ Welo, // [512,256]
    const float* __restrict__ be,
    const float* __restrict__ x,                                   // [M,512] f32
    const _Float16* __restrict__ W2hi, const _Float16* __restrict__ W2lo, // [512,512]
    const float* __restrict__ b2,
    float* __restrict__ Out)                                       // [M,512] f32
{
    __shared__ __align__(16) _Float16 As[128 * 32];
    __shared__ __align__(16) _Float16 Bs[128 * 32];

    const int tid = threadIdx.x;
    const int m0 = blockIdx.x * 128;
    const int n0 = blockIdx.y * 128;
    const int wave = tid >> 6, lane = tid & 63;
    const int wr = wave >> 1, wc = wave & 1;
    const int lq = lane >> 4, lr = lane & 15;

    f32x4 zero = {0.f, 0.f, 0.f, 0.f};
    f32x4 acc1[4][4];
#pragma unroll
    for (int i = 0; i < 4; ++i)
#pragma unroll
        for (int j = 0; j < 4; ++j) acc1[i][j] = zero;

    // phase 1: fc_end accumulation (K=256, K'=512)
    {
        const int K = HYP_;
        for (int kk = 0; kk < 2 * K; kk += 32) {
            const int ksrc = kk & (K - 1);
            const _Float16* Wseg = (kk < K) ? Wehi : Welo;
            stage_f16_tile(Wseg + (size_t)n0 * K + ksrc, K, Bs, tid);
            stage_f16_tile(h2h + (size_t)m0 * K + ksrc, K, As, tid);
            __syncthreads();
            half8_t af[4], wf[4];
#pragma unroll
            for (int i = 0; i < 4; ++i)
                af[i] = *(const half8_t*)(As + (wr * 64 + i * 16 + lr) * 32 + lq * 8);
#pragma unroll
            for (int j = 0; j < 4; ++j)
                wf[j] = *(const half8_t*)(Bs + (wc * 64 + j * 16 + lr) * 32 + lq * 8);
#pragma unroll
            for (int i = 0; i < 4; ++i)
#pragma unroll
                for (int j = 0; j < 4; ++j)
                    acc1[i][j] = __builtin_amdgcn_mfma_f32_16x16x32_f16(af[i], wf[j], acc1[i][j], 0, 0, 0);
            __syncthreads();
        }
    }

    f32x4 acc2[4][4];
#pragma unroll
    for (int i = 0; i < 4; ++i)
#pragma unroll
        for (int j = 0; j < 4; ++j) acc2[i][j] = zero;

    // phase 2: sigmoid-arm accumulation (K=512, K'=1024)
    {
        const int K = IN_;
        for (int kk = 0; kk < 2 * K; kk += 32) {
            const int ksrc = kk & (K - 1);
            const _Float16* Wseg = (kk < K) ? W2hi : W2lo;
            stage_f16_tile(Wseg + (size_t)n0 * K + ksrc, K, Bs, tid);
            stage_f32cvt_tile(x + (size_t)m0 * K + ksrc, K, As, tid);
            __syncthreads();
            half8_t af[4], wf[4];
#pragma unroll
            for (int i = 0; i < 4; ++i)
                af[i] = *(const half8_t*)(As + (wr * 64 + i * 16 + lr) * 32 + lq * 8);
#pragma unroll
            for (int j = 0; j < 4; ++j)
                wf[j] = *(const half8_t*)(Bs + (wc * 64 + j * 16 + lr) * 32 + lq * 8);
#pragma unroll
            for (int i = 0; i < 4; ++i)
#pragma unroll
                for (int j = 0; j < 4; ++j)
                    acc2[i][j] = __builtin_amdgcn_mfma_f32_16x16x32_f16(af[i], wf[j], acc2[i][j], 0, 0, 0);
            __syncthreads();
        }
    }

#pragma unroll
    for (int j = 0; j < 4; ++j) {
        const int col = n0 + wc * 64 + j * 16 + lr;
        const float bev = be[col];
        const float b2v = b2[col];
#pragma unroll
        for (int i = 0; i < 4; ++i) {
            const int rbase = m0 + wr * 64 + i * 16 + lq * 4;
#pragma unroll
            for (int rg = 0; rg < 4; ++rg) {
                float fc = acc1[i][j][rg] + bev;
                float sg = acc2[i][j][rg] + b2v;
                sg = 1.f / (1.f + __expf(-sg));
                Out[(size_t)(rbase + rg) * HID_ + col] = fc * sg;
            }
        }
    }
}

// ---------------------------------------------------------------------------
// Scan: h_t[j] = relu(h_{t-1}[(j-1)&511] + b_t[j]) decomposes into 512
// independent diagonal chains per batch: chain r touches (t, (r+t)&511).
// One thread per chain, 16-deep register prefetch, in-place over b.
// Total chains = B_*HID_ = 16384 -> 256 blocks of 64.
// ---------------------------------------------------------------------------
__global__ __launch_bounds__(64) void srnn_chain(const float* __restrict__ hidden,
                                                 float* bio, float* hlast)
{
    const int g = blockIdx.x * 64 + threadIdx.x;
    const int b = g >> 9;
    const int r = g & 511;
    float* base = bio + (size_t)b * (T_ * HID_);

    float c = hidden[b * HID_ + ((r + 511) & 511)];   // h_{-1}[(r-1) mod 512]

    float buf[16];
#pragma unroll
    for (int u = 0; u < 16; ++u)
        buf[u] = base[u * 512 + ((r + u) & 511)];

    for (int tb = 0; tb < T_; tb += 16) {
#pragma unroll
        for (int u = 0; u < 16; ++u) {
            const int t = tb + u;
            c = fmaxf(c + buf[u], 0.f);
            base[t * 512 + ((r + t) & 511)] = c;
            const int tn = t + 16;
            if (tn < T_)   // uniform branch
                buf[u] = base[tn * 512 + ((r + tn) & 511)];
        }
    }
    hlast[b * HID_ + ((r + 1023) & 511)] = c;
}

extern "C" void kernel_launch(void* const* d_in, const int* in_sizes, int n_in,
                              void* d_out, int out_size, void* d_ws, size_t ws_size,
                              hipStream_t stream)
{
    const float* x      = (const float*)d_in[0];  // [B,T,IN]
    const float* hidden = (const float*)d_in[1];  // [B,HID]
    const float* Ws     = (const float*)d_in[2];  // [HYP,IN]
    const float* bs     = (const float*)d_in[3];
    const float* Wm     = (const float*)d_in[4];  // [HYP,HYP]
    const float* bm     = (const float*)d_in[5];
    const float* We     = (const float*)d_in[6];  // [HID,HYP]
    const float* be     = (const float*)d_in[7];
    const float* W2     = (const float*)d_in[8];  // [HID,IN]
    const float* b2     = (const float*)d_in[9];

    float* outputs = (float*)d_out;                 // [B,T,HID]
    float* hlast   = outputs + (size_t)M_ * HID_;   // [B,HID]

    _Float16* h1h  = (_Float16*)d_ws;               // [M,HYP]
    _Float16* h2h  = h1h + (size_t)M_ * HYP_;       // [M,HYP]
    _Float16* wshi = h2h + (size_t)M_ * HYP_;
    _Float16* wslo = wshi + HYP_ * IN_;
    _Float16* wmhi = wslo + HYP_ * IN_;
    _Float16* wmlo = wmhi + HYP_ * HYP_;
    _Float16* wehi = wmlo + HYP_ * HYP_;
    _Float16* welo = wehi + HID_ * HYP_;
    _Float16* w2hi = welo + HID_ * HYP_;
    _Float16* w2lo = w2hi + HID_ * IN_;

    split_w<<<(HYP_ * IN_ + 255) / 256, 256, 0, stream>>>(Ws, wshi, wslo, HYP_ * IN_);
    split_w<<<(HYP_ * HYP_ + 255) / 256, 256, 0, stream>>>(Wm, wmhi, wmlo, HYP_ * HYP_);
    split_w<<<(HID_ * HYP_ + 255) / 256, 256, 0, stream>>>(We, wehi, welo, HID_ * HYP_);
    split_w<<<(HID_ * IN_ + 255) / 256, 256, 0, stream>>>(W2, w2hi, w2lo, HID_ * IN_);

    // h1 = relu(x @ Ws^T + bs)        (fp32 A, converted on stage)
    gemm_relu_f16out<false><<<dim3(M_ / 128, HYP_ / 128), 256, 0, stream>>>(
        x, nullptr, wshi, wslo, bs, h1h, HYP_, IN_);
    // h2 = relu(h1 @ Wm^T + bm)       (fp16 A)
    gemm_relu_f16out<true><<<dim3(M_ / 128, HYP_ / 128), 256, 0, stream>>>(
        nullptr, h1h, wmhi, wmlo, bm, h2h, HYP_, HYP_);
    // b = (h2 @ We^T + be) * sigmoid(x @ W2^T + b2)
    gemm_g34<<<dim3(M_ / 128, HID_ / 128), 256, 0, stream>>>(
        h2h, wehi, welo, be, x, w2hi, w2lo, b2, outputs);
    // scan (in place) + hlast: B_*HID_ = 16384 chains -> 256 blocks
    srnn_chain<<<dim3((B_ * HID_) / 64), dim3(64), 0, stream>>>(hidden, outputs, hlast);
}

// Round 4
// 172.826 us; speedup vs baseline: 3.7775x; 1.3287x over previous
//
#include <hip/hip_runtime.h>
#include <math.h>

#define B_   32
#define T_   1024
#define IN_  512
#define HID_ 512
#define HYP_ 256
#define M_   (B_ * T_)   // 32768

typedef _Float16 half8_t __attribute__((ext_vector_type(8)));
typedef float    f32x4   __attribute__((ext_vector_type(4)));

typedef __attribute__((address_space(1))) const void* gptr_as1;
typedef __attribute__((address_space(3))) void*       lptr_as3;

__device__ __forceinline__ void gload_lds16(const void* g, void* l) {
    // async global->LDS, 16B/lane; LDS dest = wave-uniform base + lane*16
    __builtin_amdgcn_global_load_lds((gptr_as1)g, (lptr_as3)l, 16, 0, 0);
}

// ---------------------------------------------------------------------------
// One fused fp32->fp16 conversion pass: x (8192 blocks) + Ws(64) + Wm(32) +
// We(64) + W2(128). Each thread converts 8 contiguous floats.
// ---------------------------------------------------------------------------
__global__ __launch_bounds__(256) void cvt_all(
    const float* __restrict__ x,  _Float16* __restrict__ xh,
    const float* __restrict__ Ws, _Float16* __restrict__ wsh,
    const float* __restrict__ Wm, _Float16* __restrict__ wmh,
    const float* __restrict__ We, _Float16* __restrict__ weh,
    const float* __restrict__ W2, _Float16* __restrict__ w2h)
{
    const int blk = blockIdx.x;
    const float* src; _Float16* dst; int base;
    if      (blk < 8192) { src = x;  dst = xh;  base = blk; }
    else if (blk < 8256) { src = Ws; dst = wsh; base = blk - 8192; }
    else if (blk < 8288) { src = Wm; dst = wmh; base = blk - 8256; }
    else if (blk < 8352) { src = We; dst = weh; base = blk - 8288; }
    else                 { src = W2; dst = w2h; base = blk - 8352; }
    const int i = base * 2048 + threadIdx.x * 8;
    f32x4 v0 = *(const f32x4*)(src + i);
    f32x4 v1 = *(const f32x4*)(src + i + 4);
    half8_t h;
    h[0] = (_Float16)v0[0]; h[1] = (_Float16)v0[1];
    h[2] = (_Float16)v0[2]; h[3] = (_Float16)v0[3];
    h[4] = (_Float16)v1[0]; h[5] = (_Float16)v1[1];
    h[6] = (_Float16)v1[2]; h[7] = (_Float16)v1[3];
    *(half8_t*)(dst + i) = h;
}

// ---------------------------------------------------------------------------
// Fragment-order LDS staging for a 128-row x 32-half tile (8 KiB).
// LDS slot s (16B each) = g*64 + c*16 + r, holding global (row g*16+r,
// k-chunk c). The wave's ds_read_b128 of fragment group g is then
// lane-contiguous (lane*16) -> conflict-free. global_load_lds writes linearly
// (dest = wave base + lane*16); the permutation lives in the SOURCE address.
// ---------------------------------------------------------------------------
__device__ __forceinline__ void stage_frag(const _Float16* src, int K,
                                           _Float16* lds, int tid)
{
#pragma unroll
    for (int q = 0; q < 2; ++q) {
        const int s = q * 256 + tid;
        const int g = s >> 6, c = (s >> 4) & 3, r = s & 15;
        const char* gp = (const char*)src + (size_t)(g * 16 + r) * (K * 2) + c * 16;
        char* lp = (char*)lds + (q * 256 + (tid & ~63)) * 16;   // wave-uniform
        gload_lds16(gp, lp);
    }
}

// ---------------------------------------------------------------------------
// C[M,N](f16) = relu(A(f16)[M,K] @ W(f16)[N,K]^T + bias). 128x128 tile, BK=32,
// 4 waves (2x2), each wave 64x64 via 4x4 frags of mfma_f32_16x16x32_f16.
// ---------------------------------------------------------------------------
__global__ __launch_bounds__(256) void gemm_relu(
    const _Float16* __restrict__ A, const _Float16* __restrict__ W,
    const float* __restrict__ bias, _Float16* __restrict__ C, int N, int K)
{
    __shared__ __align__(16) _Float16 As[128 * 32];
    __shared__ __align__(16) _Float16 Bs[128 * 32];

    const int tid = threadIdx.x;
    const int m0 = blockIdx.x * 128, n0 = blockIdx.y * 128;
    const int lane = tid & 63;
    const int wr = (tid >> 7) & 1, wc = (tid >> 6) & 1;
    const int lq = lane >> 4, lr = lane & 15;

    f32x4 zero = {0.f, 0.f, 0.f, 0.f};
    f32x4 acc[4][4];
#pragma unroll
    for (int i = 0; i < 4; ++i)
#pragma unroll
        for (int j = 0; j < 4; ++j) acc[i][j] = zero;

    const int ktiles = K >> 5;
    for (int kt = 0; kt < ktiles; ++kt) {
        stage_frag(A + (size_t)m0 * K + kt * 32, K, As, tid);
        stage_frag(W + (size_t)n0 * K + kt * 32, K, Bs, tid);
        __syncthreads();

        half8_t af[4], wf[4];
#pragma unroll
        for (int i = 0; i < 4; ++i)
            af[i] = *(const half8_t*)((const char*)As + (wr * 4 + i) * 1024 + lane * 16);
#pragma unroll
        for (int j = 0; j < 4; ++j)
            wf[j] = *(const half8_t*)((const char*)Bs + (wc * 4 + j) * 1024 + lane * 16);
#pragma unroll
        for (int i = 0; i < 4; ++i)
#pragma unroll
            for (int j = 0; j < 4; ++j)
                acc[i][j] = __builtin_amdgcn_mfma_f32_16x16x32_f16(af[i], wf[j], acc[i][j], 0, 0, 0);
        __syncthreads();
    }

#pragma unroll
    for (int j = 0; j < 4; ++j) {
        const int col = n0 + wc * 64 + j * 16 + lr;
        const float bv = bias[col];
#pragma unroll
        for (int i = 0; i < 4; ++i) {
            const int rbase = m0 + wr * 64 + i * 16 + lq * 4;
#pragma unroll
            for (int rg = 0; rg < 4; ++rg) {
                float v = acc[i][j][rg] + bv;
                C[(size_t)(rbase + rg) * N + col] = (_Float16)fmaxf(v, 0.f);
            }
        }
    }
}

// ---------------------------------------------------------------------------
// Fused G3+G4: Out(f32) = (h2 @ We^T + be) * sigmoid(xh @ W2^T + b2).
// Two sequential K-loops into two accumulator sets, shared LDS.
// ---------------------------------------------------------------------------
__global__ __launch_bounds__(256) void gemm_g34(
    const _Float16* __restrict__ h2h, const _Float16* __restrict__ weh,
    const float* __restrict__ be,
    const _Float16* __restrict__ xh, const _Float16* __restrict__ w2h,
    const float* __restrict__ b2,
    float* __restrict__ Out)
{
    __shared__ __align__(16) _Float16 As[128 * 32];
    __shared__ __align__(16) _Float16 Bs[128 * 32];

    const int tid = threadIdx.x;
    const int m0 = blockIdx.x * 128, n0 = blockIdx.y * 128;
    const int lane = tid & 63;
    const int wr = (tid >> 7) & 1, wc = (tid >> 6) & 1;
    const int lq = lane >> 4, lr = lane & 15;

    f32x4 zero = {0.f, 0.f, 0.f, 0.f};
    f32x4 acc1[4][4], acc2[4][4];
#pragma unroll
    for (int i = 0; i < 4; ++i)
#pragma unroll
        for (int j = 0; j < 4; ++j) { acc1[i][j] = zero; acc2[i][j] = zero; }

    // phase 1: fc_end arm (K=256, 8 k-tiles)
    for (int kt = 0; kt < HYP_ / 32; ++kt) {
        stage_frag(h2h + (size_t)m0 * HYP_ + kt * 32, HYP_, As, tid);
        stage_frag(weh + (size_t)n0 * HYP_ + kt * 32, HYP_, Bs, tid);
        __syncthreads();
        half8_t af[4], wf[4];
#pragma unroll
        for (int i = 0; i < 4; ++i)
            af[i] = *(const half8_t*)((const char*)As + (wr * 4 + i) * 1024 + lane * 16);
#pragma unroll
        for (int j = 0; j < 4; ++j)
            wf[j] = *(const half8_t*)((const char*)Bs + (wc * 4 + j) * 1024 + lane * 16);
#pragma unroll
        for (int i = 0; i < 4; ++i)
#pragma unroll
            for (int j = 0; j < 4; ++j)
                acc1[i][j] = __builtin_amdgcn_mfma_f32_16x16x32_f16(af[i], wf[j], acc1[i][j], 0, 0, 0);
        __syncthreads();
    }

    // phase 2: sigmoid arm (K=512, 16 k-tiles)
    for (int kt = 0; kt < IN_ / 32; ++kt) {
        stage_frag(xh + (size_t)m0 * IN_ + kt * 32, IN_, As, tid);
        stage_frag(w2h + (size_t)n0 * IN_ + kt * 32, IN_, Bs, tid);
        __syncthreads();
        half8_t af[4], wf[4];
#pragma unroll
        for (int i = 0; i < 4; ++i)
            af[i] = *(const half8_t*)((const char*)As + (wr * 4 + i) * 1024 + lane * 16);
#pragma unroll
        for (int j = 0; j < 4; ++j)
            wf[j] = *(const half8_t*)((const char*)Bs + (wc * 4 + j) * 1024 + lane * 16);
#pragma unroll
        for (int i = 0; i < 4; ++i)
#pragma unroll
            for (int j = 0; j < 4; ++j)
                acc2[i][j] = __builtin_amdgcn_mfma_f32_16x16x32_f16(af[i], wf[j], acc2[i][j], 0, 0, 0);
        __syncthreads();
    }

#pragma unroll
    for (int j = 0; j < 4; ++j) {
        const int col = n0 + wc * 64 + j * 16 + lr;
        const float bev = be[col];
        const float b2v = b2[col];
#pragma unroll
        for (int i = 0; i < 4; ++i) {
            const int rbase = m0 + wr * 64 + i * 16 + lq * 4;
#pragma unroll
            for (int rg = 0; rg < 4; ++rg) {
                float fc = acc1[i][j][rg] + bev;
                float sg = acc2[i][j][rg] + b2v;
                sg = 1.f / (1.f + __expf(-sg));
                Out[(size_t)(rbase + rg) * HID_ + col] = fc * sg;
            }
        }
    }
}

// ---------------------------------------------------------------------------
// Scan: h_t[j] = relu(h_{t-1}[(j-1)&511] + b_t[j]) -> 512 independent
// diagonal chains per batch (chain r touches (t, (r+t)&511)). One thread per
// chain, 16-deep register prefetch, in-place over b. 16384 chains.
// ---------------------------------------------------------------------------
__global__ __launch_bounds__(64) void srnn_chain(const float* __restrict__ hidden,
                                                 float* bio, float* hlast)
{
    const int g = blockIdx.x * 64 + threadIdx.x;
    const int b = g >> 9;
    const int r = g & 511;
    float* base = bio + (size_t)b * (T_ * HID_);

    float c = hidden[b * HID_ + ((r + 511) & 511)];   // h_{-1}[(r-1) mod 512]

    float buf[16];
#pragma unroll
    for (int u = 0; u < 16; ++u)
        buf[u] = base[u * 512 + ((r + u) & 511)];

    for (int tb = 0; tb < T_; tb += 16) {
#pragma unroll
        for (int u = 0; u < 16; ++u) {
            const int t = tb + u;
            c = fmaxf(c + buf[u], 0.f);
            base[t * 512 + ((r + t) & 511)] = c;
            const int tn = t + 16;
            if (tn < T_)   // uniform branch
                buf[u] = base[tn * 512 + ((r + tn) & 511)];
        }
    }
    hlast[b * HID_ + ((r + 1023) & 511)] = c;
}

extern "C" void kernel_launch(void* const* d_in, const int* in_sizes, int n_in,
                              void* d_out, int out_size, void* d_ws, size_t ws_size,
                              hipStream_t stream)
{
    const float* x      = (const float*)d_in[0];  // [B,T,IN]
    const float* hidden = (const float*)d_in[1];  // [B,HID]
    const float* Ws     = (const float*)d_in[2];  // [HYP,IN]
    const float* bs     = (const float*)d_in[3];
    const float* Wm     = (const float*)d_in[4];  // [HYP,HYP]
    const float* bm     = (const float*)d_in[5];
    const float* We     = (const float*)d_in[6];  // [HID,HYP]
    const float* be     = (const float*)d_in[7];
    const float* W2     = (const float*)d_in[8];  // [HID,IN]
    const float* b2     = (const float*)d_in[9];

    float* outputs = (float*)d_out;                 // [B,T,HID]
    float* hlast   = outputs + (size_t)M_ * HID_;   // [B,HID]

    // workspace: xh 32MB | h2h 16MB | 4 fp16 weights ~1.2MB  (~49MB total)
    _Float16* xh  = (_Float16*)d_ws;                // [M,IN]
    _Float16* h2h = xh + (size_t)M_ * IN_;          // [M,HYP]
    _Float16* wsh = h2h + (size_t)M_ * HYP_;        // [HYP,IN]
    _Float16* wmh = wsh + HYP_ * IN_;               // [HYP,HYP]
    _Float16* weh = wmh + HYP_ * HYP_;              // [HID,HYP]
    _Float16* w2h = weh + HID_ * HYP_;              // [HID,IN]

    // h1 (16MB fp16) staged in the front of d_out; dead before gemm_g34
    // overwrites the region (kernels are stream-ordered).
    _Float16* h1h = (_Float16*)d_out;

    // fp32 -> fp16: x and all weights, one pass
    cvt_all<<<dim3(8480), 256, 0, stream>>>(x, xh, Ws, wsh, Wm, wmh, We, weh, W2, w2h);
    // h1 = relu(xh @ Ws^T + bs)
    gemm_relu<<<dim3(M_ / 128, HYP_ / 128), 256, 0, stream>>>(xh, wsh, bs, h1h, HYP_, IN_);
    // h2 = relu(h1 @ Wm^T + bm)
    gemm_relu<<<dim3(M_ / 128, HYP_ / 128), 256, 0, stream>>>(h1h, wmh, bm, h2h, HYP_, HYP_);
    // outputs = (h2 @ We^T + be) * sigmoid(xh @ W2^T + b2)
    gemm_g34<<<dim3(M_ / 128, HID_ / 128), 256, 0, stream>>>(h2h, weh, be, xh, w2h, b2, outputs);
    // scan (in place) + hlast
    srnn_chain<<<dim3((B_ * HID_) / 64), dim3(64), 0, stream>>>(hidden, outputs, hlast);
}